// Round 1
// baseline (3265.067 us; speedup 1.0000x reference)
//
#include <hip/hip_runtime.h>
#include <stdint.h>

#define NEGV  (-1000000000.0f)
#define CONF  0.05f
#define IOUT  0.15f
#define MAXSEL 550
#define CAP   32768

// Bit-exact IoU > 0.15 test, replicating the JAX f32 op sequence without FMA contraction.
__device__ __forceinline__ bool iou_gt(float ax, float ay, float az, float aw,
                                       float bx, float by, float bz, float bw) {
    float ltx = fmaxf(ax, bx), lty = fmaxf(ay, by);
    float rbx = fminf(az, bz), rby = fminf(aw, bw);
    float wx = fmaxf(__fsub_rn(rbx, ltx), 0.0f);
    float wy = fmaxf(__fsub_rn(rby, lty), 0.0f);
    float inter = __fmul_rn(wx, wy);
    float aA = __fmul_rn(fmaxf(__fsub_rn(az, ax), 0.0f), fmaxf(__fsub_rn(aw, ay), 0.0f));
    float aB = __fmul_rn(fmaxf(__fsub_rn(bz, bx), 0.0f), fmaxf(__fsub_rn(bw, by), 0.0f));
    float uni = __fsub_rn(__fadd_rn(aA, aB), inter);
    float iou = __fdiv_rn(inter, fmaxf(uni, 1e-8f));
    return iou > IOUT;
}

// K1: decode cxcywh -> corner boxes for all (b,n)
__global__ void k_decode(const float* __restrict__ pred, float4* __restrict__ boxes, int BN) {
    int t = blockIdx.x * 256 + threadIdx.x;
    if (t >= BN) return;
    const float* p = pred + (size_t)t * 6;
    float cx = p[0], cy = p[1], w = p[2], h = p[3];
    float hw = __fmul_rn(w, 0.5f), hh = __fmul_rn(h, 0.5f);
    float4 b;
    b.x = __fsub_rn(cx, hw);
    b.y = __fsub_rn(cy, hh);
    b.z = __fadd_rn(cx, hw);
    b.w = __fadd_rn(cy, hh);
    boxes[t] = b;
}

// K2: per (b,c) deterministic order-preserving compaction of candidates with sigmoid > CONF.
// key = (~score_bits << 32) | n : ascending u64 sort == (score desc, n asc).
__global__ __launch_bounds__(1024) void k_compact(const float* __restrict__ pred,
                                                  unsigned long long* __restrict__ keys,
                                                  unsigned int* __restrict__ cnt,
                                                  int Nn, int Cc) {
    int bc = blockIdx.x;
    int b = bc / Cc, c = bc % Cc;
    int tid = threadIdx.x, lane = tid & 63, wid = tid >> 6;
    __shared__ unsigned int wsum[16];
    __shared__ unsigned int sbase, stot;
    if (tid == 0) sbase = 0;
    __syncthreads();
    unsigned long long* kk = keys + (size_t)bc * CAP;
    for (int tile = 0; tile < Nn; tile += 1024) {
        int n = tile + tid;
        bool p = false;
        float sc = 0.f;
        if (n < Nn) {
            float lg = pred[((size_t)b * Nn + n) * 6 + 4 + c];
            sc = __fdiv_rn(1.0f, __fadd_rn(1.0f, expf(-lg)));
            p = sc > CONF;
        }
        unsigned long long m = __ballot(p);
        if (lane == 0) wsum[wid] = (unsigned)__popcll(m);
        __syncthreads();
        if (tid == 0) {
            unsigned run = 0;
            for (int w2 = 0; w2 < 16; ++w2) { unsigned t2 = wsum[w2]; wsum[w2] = run; run += t2; }
            stot = run;
        }
        __syncthreads();
        if (p) {
            unsigned rank = (unsigned)__popcll(m & ((1ull << lane) - 1ull));
            unsigned pos = sbase + wsum[wid] + rank;
            if (pos < CAP)
                kk[pos] = (((unsigned long long)(~__float_as_uint(sc))) << 32) | (unsigned)n;
        }
        __syncthreads();
        if (tid == 0) sbase += stot;
        __syncthreads();
    }
    unsigned total = sbase;
    unsigned cv = total < CAP ? total : CAP;
    if (tid == 0) cnt[bc] = cv;
    for (unsigned i = cv + tid; i < CAP; i += 1024) kk[i] = ~0ull;
}

// K3: one-block global-memory bitonic sort of CAP u64 keys, ascending.
__global__ __launch_bounds__(1024) void k_sort(unsigned long long* __restrict__ keys) {
    unsigned long long* a = keys + (size_t)blockIdx.x * CAP;
    for (int k = 2; k <= CAP; k <<= 1) {
        for (int j = k >> 1; j > 0; j >>= 1) {
            __syncthreads();
            for (int idx = threadIdx.x; idx < CAP / 2; idx += 1024) {
                int i = ((idx & ~(j - 1)) << 1) | (idx & (j - 1));
                int p = i | j;
                bool up = ((i & k) == 0);
                unsigned long long x = a[i], y = a[p];
                if ((x > y) == up) { a[i] = y; a[p] = x; }
            }
        }
    }
}

// K4: chunked greedy NMS over the sorted candidate list.
__global__ __launch_bounds__(1024) void k_nms(const unsigned long long* __restrict__ keys,
                                              const unsigned int* __restrict__ cnt,
                                              const float4* __restrict__ boxes,
                                              unsigned int* __restrict__ sel_n,
                                              float* __restrict__ sel_s,
                                              unsigned int* __restrict__ selcnt,
                                              int Nn, int Cc) {
    int bc = blockIdx.x;
    int b = bc / Cc;
    int tid = threadIdx.x;
    __shared__ float4 selb[MAXSEL];
    __shared__ float4 chb[1024];
    __shared__ float chs[1024];
    __shared__ unsigned int chn[1024];
    __shared__ int salive[1024];
    __shared__ int s_selcnt, s_done;
    if (tid == 0) { s_selcnt = 0; s_done = 0; }
    __syncthreads();
    unsigned cv = cnt[bc];
    const unsigned long long* kk = keys + (size_t)bc * CAP;
    unsigned int* out_n = sel_n + (size_t)bc * MAXSEL;
    float* out_s = sel_s + (size_t)bc * MAXSEL;
    for (unsigned start = 0; start < cv; start += 1024) {
        int S0 = s_selcnt;
        unsigned i = start + tid;
        bool al = (i < cv);
        float4 bx = make_float4(0.f, 0.f, 0.f, 0.f);
        float scv = 0.f;
        unsigned nv = 0;
        if (al) {
            unsigned long long key = kk[i];
            nv = (unsigned)(key & 0xffffffffull);
            scv = __uint_as_float(~(unsigned)(key >> 32));
            bx = boxes[(size_t)b * Nn + nv];
            // phase 1: test vs already-selected (before this chunk)
            for (int s = 0; s < S0; ++s) {
                float4 sb = selb[s];
                if (iou_gt(bx.x, bx.y, bx.z, bx.w, sb.x, sb.y, sb.z, sb.w)) { al = false; break; }
            }
        }
        chb[tid] = bx; chs[tid] = scv; chn[tid] = nv; salive[tid] = al ? 1 : 0;
        __syncthreads();
        // phase 2: wave 0 resolves intra-chunk ordering wave-synchronously
        if (tid < 64) {
            int lane = tid;
            int lsel = s_selcnt;
            bool fin = false;
            for (int g = 0; g < 16 && !fin; ++g) {
                int ci = (g << 6) | lane;
                bool a = salive[ci] != 0;
                float4 cb = chb[ci];
                float cs = chs[ci];
                unsigned cn = chn[ci];
                // test vs boxes selected earlier within this chunk
                for (int s = S0; s < lsel && a; ++s) {
                    float4 sb = selb[s];
                    if (iou_gt(cb.x, cb.y, cb.z, cb.w, sb.x, sb.y, sb.z, sb.w)) a = false;
                }
                unsigned long long m = __ballot(a);
                while (m) {
                    int kl = __builtin_ctzll(m);
                    float b0x = __shfl(cb.x, kl);
                    float b0y = __shfl(cb.y, kl);
                    float b0z = __shfl(cb.z, kl);
                    float b0w = __shfl(cb.w, kl);
                    if (lane == kl) {
                        selb[lsel] = cb;
                        out_n[lsel] = cn;
                        out_s[lsel] = cs;
                    }
                    ++lsel;
                    if (lsel >= MAXSEL) { fin = true; break; }
                    if (a && iou_gt(cb.x, cb.y, cb.z, cb.w, b0x, b0y, b0z, b0w)) a = false;
                    m = __ballot(a);
                }
            }
            if (lane == 0) { s_selcnt = lsel; if (fin) s_done = 1; }
        }
        __syncthreads();
        if (s_done) break;
    }
    if (tid == 0) selcnt[bc] = (unsigned)s_selcnt;
}

// K5: per-batch merge of the C*MAXSEL selections (== jax.lax.top_k full sort) + output write.
__global__ __launch_bounds__(1024) void k_final(const unsigned int* __restrict__ selcnt,
                                                const unsigned int* __restrict__ sel_n,
                                                const float* __restrict__ sel_s,
                                                const float4* __restrict__ boxes,
                                                float* __restrict__ out,
                                                int Nn, int Cc, int Bb) {
    int b = blockIdx.x, tid = threadIdx.x;
    const int TOT = MAXSEL * 2;   // 1100
    __shared__ unsigned long long sk[2048];
    unsigned c0 = selcnt[b * Cc + 0];
    unsigned c1 = selcnt[b * Cc + 1];
    for (int t = tid; t < 2048; t += 1024) {
        unsigned long long key;
        if (t < TOT) {
            int c = t / MAXSEL, k2 = t % MAXSEL;
            unsigned cc = (c == 0) ? c0 : c1;
            float sc = (k2 < (int)cc) ? sel_s[(size_t)(b * Cc + c) * MAXSEL + k2] : NEGV;
            unsigned u = __float_as_uint(sc);
            unsigned ord = (u & 0x80000000u) ? ~u : (u | 0x80000000u);
            key = (((unsigned long long)(~ord)) << 32) | (unsigned)t;
        } else {
            key = ~0ull;
        }
        sk[t] = key;
    }
    __syncthreads();
    for (int k = 2; k <= 2048; k <<= 1) {
        for (int j = k >> 1; j > 0; j >>= 1) {
            int idx = tid;  // exactly 1024 pairs
            int i = ((idx & ~(j - 1)) << 1) | (idx & (j - 1));
            int p = i | j;
            bool up = ((i & k) == 0);
            unsigned long long x = sk[i], y = sk[p];
            if ((x > y) == up) { sk[i] = y; sk[p] = x; }
            __syncthreads();
        }
    }
    int off_scores = Bb * TOT * 4;                 // 17600
    int off_classes = off_scores + Bb * TOT;       // 22000
    int off_valid = off_classes + Bb * TOT;        // 26400
    for (int r = tid; r < TOT; r += 1024) {
        unsigned long long key = sk[r];
        unsigned flat = (unsigned)(key & 0xffffffffull);
        unsigned hi = (unsigned)(key >> 32);
        unsigned ord = ~hi;
        float sc = (ord & 0x80000000u) ? __uint_as_float(ord & 0x7fffffffu)
                                       : __uint_as_float(~ord);
        bool valid = sc > -5.0e8f;
        int c = (int)(flat / MAXSEL), k2 = (int)(flat % MAXSEL);
        float4 bxv = make_float4(0.f, 0.f, 0.f, 0.f);
        float so = 0.f, co = 0.f;
        if (valid) {
            unsigned n = sel_n[(size_t)(b * Cc + c) * MAXSEL + k2];
            bxv = boxes[(size_t)b * Nn + n];
            so = sc;
            co = (float)c;
        }
        ((float4*)out)[b * TOT + r] = bxv;
        out[off_scores + b * TOT + r] = so;
        out[off_classes + b * TOT + r] = co;
    }
    if (tid == 0) out[off_valid + b] = (float)(c0 + c1);
}

extern "C" void kernel_launch(void* const* d_in, const int* in_sizes, int n_in,
                              void* d_out, int out_size, void* d_ws, size_t ws_size,
                              hipStream_t stream) {
    const float* pred = (const float*)d_in[1];
    float* out = (float*)d_out;
    int Bb = out_size / 6601;            // 4   (1100*6 + 1 floats per batch)
    int Nn = in_sizes[1] / (6 * Bb);     // 49104
    const int Cc = 2;
    if (Bb <= 0 || Nn <= 0) return;

    char* ws = (char*)d_ws;
    size_t off = 0;
    float4* boxes = (float4*)(ws + off);
    off += (size_t)Bb * Nn * 16;             off = (off + 255) & ~(size_t)255;
    unsigned long long* keys = (unsigned long long*)(ws + off);
    off += (size_t)Bb * Cc * CAP * 8;        off = (off + 255) & ~(size_t)255;
    unsigned int* cnt = (unsigned int*)(ws + off);
    off += (size_t)Bb * Cc * 4;              off = (off + 255) & ~(size_t)255;
    unsigned int* sel_n = (unsigned int*)(ws + off);
    off += (size_t)Bb * Cc * MAXSEL * 4;     off = (off + 255) & ~(size_t)255;
    float* sel_s = (float*)(ws + off);
    off += (size_t)Bb * Cc * MAXSEL * 4;     off = (off + 255) & ~(size_t)255;
    unsigned int* selcnt = (unsigned int*)(ws + off);

    int BN = Bb * Nn;
    k_decode<<<(BN + 255) / 256, 256, 0, stream>>>(pred, boxes, BN);
    k_compact<<<Bb * Cc, 1024, 0, stream>>>(pred, keys, cnt, Nn, Cc);
    k_sort<<<Bb * Cc, 1024, 0, stream>>>(keys);
    k_nms<<<Bb * Cc, 1024, 0, stream>>>(keys, cnt, boxes, sel_n, sel_s, selcnt, Nn, Cc);
    k_final<<<Bb, 1024, 0, stream>>>(selcnt, sel_n, sel_s, boxes, out, Nn, Cc, Bb);
}